// Round 2
// baseline (811.691 us; speedup 1.0000x reference)
//
#include <hip/hip_runtime.h>
#include <hip/hip_bf16.h>

// DIN sequence encoder, B=4096 L=200 E=A=128. Inputs/outputs are FP32
// (round-1 NaN => fp32 data was being misread as bf16; threshold analysis
// confirms _any_bf16=False). Compute path: convert to bf16 for MFMA,
// accumulate fp32.
//
// Algebra: att_in@W1 = q@(W1a+W1c) + kp@(W1b-W1c) + (q*kp)@W1d
//        = [per-b vector qW] + kp @ W1eff,  W1eff = Wk + diag(q)*Wqk
// so GEMM1 is K=128 instead of K=512, and q@Wq is a per-row fp32 GEMV.

typedef __attribute__((ext_vector_type(8))) short short8;
typedef __attribute__((ext_vector_type(4))) float f32x4;

__device__ __forceinline__ float bf2f(short s) {
    return __uint_as_float(((unsigned)(unsigned short)s) << 16);
}
__device__ __forceinline__ short f2bf(float f) {
    unsigned u = __float_as_uint(f);
    u = (u + 0x7fff + ((u >> 16) & 1)) >> 16;   // RNE; inputs finite
    return (short)u;
}

// ---- prep 1: transposed bf16 weight blocks into ws -------------------------
__global__ void prep_w(const float* __restrict__ W1, const float* __restrict__ W2,
                       short* __restrict__ wkT, short* __restrict__ wqkT,
                       short* __restrict__ w2T) {
    int i = blockIdx.x * 256 + threadIdx.x;      // 16384 elements
    int k = i >> 7, n = i & 127;                 // reads coalesced over n
    wkT [n * 128 + k] = f2bf(W1[(128 + k) * 128 + n] - W1[(256 + k) * 128 + n]);
    wqkT[n * 128 + k] = f2bf(W1[(384 + k) * 128 + n]);
    w2T [n * 128 + k] = f2bf(W2[k * 128 + n]);
}

// ---- prep 2: qW[b][n] = b1[n] + sum_k q[b][k]*(W1a+W1c)[k][n]  (fp32) ------
__global__ void prep_qw(const float* __restrict__ query, const float* __restrict__ W1,
                        const float* __restrict__ b1, float* __restrict__ qw) {
    __shared__ float qsh[128];
    const int b = blockIdx.x, t = threadIdx.x;   // 128 threads
    qsh[t] = query[b * 128 + t];
    __syncthreads();
    float acc = b1[t];
    #pragma unroll 4
    for (int k = 0; k < 128; ++k)
        acc += qsh[k] * (W1[k * 128 + t] + W1[(256 + k) * 128 + t]);
    qw[b * 128 + t] = acc;
}

// ---- main: one workgroup per batch row -------------------------------------
#define STR 136  // LDS row stride (bf16 elems): keeps 16B align, breaks pow2 banks

__launch_bounds__(256, 1)
__global__ void din_main(const float* __restrict__ query, const float* __restrict__ keys,
                         const int* __restrict__ klen, const float* __restrict__ pos,
                         const float* __restrict__ b2g, const float* __restrict__ w3g,
                         const float* __restrict__ qw, const short* __restrict__ wkT,
                         const short* __restrict__ wqkT, const short* __restrict__ w2Tg,
                         float* __restrict__ out) {
    __shared__ alignas(16) short kp[208 * STR];      // keys+pos (bf16), persistent
    __shared__ alignas(16) short w1eff[128 * STR];   // [n][k] transposed
    __shared__ alignas(16) short w2t[128 * STR];     // [n][k] transposed
    __shared__ alignas(16) short h1s[4 * 16 * STR];  // per-wave h1 staging
    __shared__ float qv[128];
    __shared__ float s_lds[208];
    __shared__ float w_lds[208];
    __shared__ float part[4 * 128];
    __shared__ float red[8];

    const int t = threadIdx.x;
    const int b = blockIdx.x;
    const int w = t >> 6;
    const int lane = t & 63;
    const int quad = lane >> 4;
    const int l15 = lane & 15;

    if (t < 128) qv[t] = query[b * 128 + t];
    __syncthreads();

    // build W1eff^T = WkT + q[k]*WqkT  (bf16), copy W2T into padded LDS
    for (int i = t; i < 8192; i += 256) {
        int n = i >> 6, kk = (i & 63) * 2;
        unsigned a = *(const unsigned*)(wkT + n * 128 + kk);
        unsigned c = *(const unsigned*)(wqkT + n * 128 + kk);
        float v0 = bf2f((short)(a & 0xffff)) + qv[kk]     * bf2f((short)(c & 0xffff));
        float v1 = bf2f((short)(a >> 16))    + qv[kk + 1] * bf2f((short)(c >> 16));
        *(unsigned*)(w1eff + n * STR + kk) =
            (unsigned)(unsigned short)f2bf(v0) | ((unsigned)(unsigned short)f2bf(v1) << 16);
    }
    for (int i = t; i < 2048; i += 256) {
        int n = i >> 4, seg = (i & 15) * 8;
        *(short8*)(w2t + n * STR + seg) = *(const short8*)(w2Tg + n * 128 + seg);
    }

    // per-lane column constants (col = n*16 + l15)
    float qwn[8], b2n[8], w3n[8];
    #pragma unroll
    for (int n = 0; n < 8; ++n) {
        qwn[n] = qw[b * 128 + n * 16 + l15];
        b2n[n] = b2g[n * 16 + l15];
        w3n[n] = w3g[n * 16 + l15];
    }
    __syncthreads();

    short* h1w = h1s + w * 16 * STR;

    for (int tile = w; tile < 13; tile += 4) {
        // stage kp rows (16 rows x 128 fp32 -> bf16) -- coalesced 512B/row reads
        #pragma unroll
        for (int i = 0; i < 4; ++i) {
            int row = quad + 4 * i;
            int l = tile * 16 + row;
            short8 kp8;
            if (l < 200) {
                const float4* kr = (const float4*)(keys + ((long)b * 200 + l) * 128);
                const float4* pr = (const float4*)(pos + (long)l * 128);
                float4 k0 = kr[l15 * 2], k1 = kr[l15 * 2 + 1];
                float4 p0 = pr[l15 * 2], p1 = pr[l15 * 2 + 1];
                kp8[0] = f2bf(k0.x + p0.x); kp8[1] = f2bf(k0.y + p0.y);
                kp8[2] = f2bf(k0.z + p0.z); kp8[3] = f2bf(k0.w + p0.w);
                kp8[4] = f2bf(k1.x + p1.x); kp8[5] = f2bf(k1.y + p1.y);
                kp8[6] = f2bf(k1.z + p1.z); kp8[7] = f2bf(k1.w + p1.w);
            } else {
                #pragma unroll
                for (int j = 0; j < 8; ++j) kp8[j] = 0;
            }
            *(short8*)(kp + (tile * 16 + row) * STR + l15 * 8) = kp8;
        }

        // GEMM1: (16x128) = kp_tile @ W1eff
        f32x4 acc[8];
        #pragma unroll
        for (int n = 0; n < 8; ++n) acc[n] = (f32x4){0.f, 0.f, 0.f, 0.f};
        #pragma unroll
        for (int s = 0; s < 4; ++s) {
            short8 a = *(const short8*)(kp + (tile * 16 + l15) * STR + s * 32 + quad * 8);
            #pragma unroll
            for (int n = 0; n < 8; ++n) {
                short8 bb = *(const short8*)(w1eff + (n * 16 + l15) * STR + s * 32 + quad * 8);
                acc[n] = __builtin_amdgcn_mfma_f32_16x16x32_bf16(a, bb, acc[n], 0, 0, 0);
            }
        }
        // h1 = relu(acc + qW) -> bf16 staging (C-layout -> A-layout via LDS)
        #pragma unroll
        for (int n = 0; n < 8; ++n) {
            #pragma unroll
            for (int r = 0; r < 4; ++r) {
                float v = acc[n][r] + qwn[n];
                h1w[(quad * 4 + r) * STR + n * 16 + l15] = f2bf(v > 0.f ? v : 0.f);
            }
        }
        // GEMM2: (16x128) = h1 @ W2
        #pragma unroll
        for (int n = 0; n < 8; ++n) acc[n] = (f32x4){0.f, 0.f, 0.f, 0.f};
        #pragma unroll
        for (int s = 0; s < 4; ++s) {
            short8 a = *(const short8*)(h1w + l15 * STR + s * 32 + quad * 8);
            #pragma unroll
            for (int n = 0; n < 8; ++n) {
                short8 bb = *(const short8*)(w2t + (n * 16 + l15) * STR + s * 32 + quad * 8);
                acc[n] = __builtin_amdgcn_mfma_f32_16x16x32_bf16(a, bb, acc[n], 0, 0, 0);
            }
        }
        // scores: s[m] = sum_n relu(h2+b2)*W3[n]; reduce over 16 lanes of quad
        float p[4] = {0.f, 0.f, 0.f, 0.f};
        #pragma unroll
        for (int n = 0; n < 8; ++n) {
            #pragma unroll
            for (int r = 0; r < 4; ++r) {
                float v = acc[n][r] + b2n[n];
                p[r] += (v > 0.f ? v : 0.f) * w3n[n];
            }
        }
        #pragma unroll
        for (int off = 8; off >= 1; off >>= 1) {
            #pragma unroll
            for (int r = 0; r < 4; ++r) p[r] += __shfl_xor(p[r], off, 64);
        }
        if (l15 == 0) {
            #pragma unroll
            for (int r = 0; r < 4; ++r) s_lds[tile * 16 + quad * 4 + r] = p[r];
        }
    }
    __syncthreads();

    // masked softmax over L (b3 dropped: softmax is shift-invariant)
    const int len = klen[b];
    float sv = (t < 208 && t < len) ? s_lds[t] : -1e9f;
    float m = sv;
    #pragma unroll
    for (int off = 32; off >= 1; off >>= 1) m = fmaxf(m, __shfl_xor(m, off, 64));
    if (lane == 0) red[w] = m;
    __syncthreads();
    m = fmaxf(fmaxf(red[0], red[1]), fmaxf(red[2], red[3]));
    float e = (t < 208) ? expf(sv - m) : 0.f;   // masked -> exp(-1e9-m) -> 0
    float ssum = e;
    #pragma unroll
    for (int off = 32; off >= 1; off >>= 1) ssum += __shfl_xor(ssum, off, 64);
    if (lane == 0) red[4 + w] = ssum;
    __syncthreads();
    float S = red[4] + red[5] + red[6] + red[7];
    if (t < 208) w_lds[t] = e / S;
    __syncthreads();

    // out[b][e] = sum_l w[l]*kp[l][e]  (4 l-quarters x 64 e-pairs)
    const int qt = t >> 6;
    const int e2 = (t & 63) * 2;
    float ax = 0.f, ay = 0.f;
    for (int l = qt * 52; l < qt * 52 + 52; ++l) {
        float wgt = w_lds[l];
        unsigned pr = *(const unsigned*)(kp + l * STR + e2);
        ax += wgt * __uint_as_float(pr << 16);
        ay += wgt * __uint_as_float(pr & 0xffff0000u);
    }
    part[qt * 128 + e2] = ax;
    part[qt * 128 + e2 + 1] = ay;
    __syncthreads();
    if (t < 128) {
        float o = part[t] + part[128 + t] + part[256 + t] + part[384 + t];
        out[b * 128 + t] = o;
    }
}

extern "C" void kernel_launch(void* const* d_in, const int* in_sizes, int n_in,
                              void* d_out, int out_size, void* d_ws, size_t ws_size,
                              hipStream_t stream) {
    const float* query = (const float*)d_in[0];
    const float* keys  = (const float*)d_in[1];
    const int*   klen  = (const int*)  d_in[2];
    const float* pos   = (const float*)d_in[3];
    const float* W1    = (const float*)d_in[4];
    const float* b1    = (const float*)d_in[5];
    const float* W2    = (const float*)d_in[6];
    const float* b2    = (const float*)d_in[7];
    const float* W3    = (const float*)d_in[8];
    // d_in[9] = b3: shift-invariant under softmax, unused.
    float* out = (float*)d_out;

    char* ws = (char*)d_ws;
    float* qw   = (float*)ws;                         // 4096*128 fp32 = 2 MiB
    short* wkT  = (short*)(ws + 2097152);             // 128*128 bf16
    short* wqkT = (short*)(ws + 2097152 + 32768);
    short* w2T  = (short*)(ws + 2097152 + 65536);

    prep_w  <<<64,   256, 0, stream>>>(W1, W2, wkT, wqkT, w2T);
    prep_qw <<<4096, 128, 0, stream>>>(query, W1, b1, qw);
    din_main<<<4096, 256, 0, stream>>>(query, keys, klen, pos, b2, W3, qw,
                                       wkT, wqkT, w2T, out);
}

// Round 3
// 715.673 us; speedup vs baseline: 1.1342x; 1.1342x over previous
//
#include <hip/hip_runtime.h>
#include <hip/hip_bf16.h>

// DIN sequence encoder, B=4096 L=200 E=A=128, fp32 I/O, bf16 MFMA compute.
//
// v3: K=256 formulation  att_in@W1 = qW[b] + [kp | kp*q] @ [Wk; Wqk]
//     (Wk = W1b-W1c, Wqk = W1d, qW = b1 + q@(W1a+W1c))
//  - B is batch-invariant -> frag-ordered in global ws, read coalesced (L1/L2)
//  - A-frags built in registers straight from global keys (no LDS staging)
//  - only ceil(len/16) L-tiles computed (masked tail skipped entirely)
//  - each wave owns up to 4 M-tiles -> B-frag amortized over 4 MFMAs
//  - LDS ~74 KB -> 2 blocks/CU; GEMM phase has no __syncthreads
//  - weighted sum re-reads keys (L2/L3-hot, ~us after first read)

typedef __attribute__((ext_vector_type(8))) short short8;
typedef __attribute__((ext_vector_type(4))) float f32x4;

__device__ __forceinline__ float bf2f(short s) {
    return __uint_as_float(((unsigned)(unsigned short)s) << 16);
}
__device__ __forceinline__ short f2bf(float f) {
    unsigned u = __float_as_uint(f);
    u = (u + 0x7fff + ((u >> 16) & 1)) >> 16;   // RNE; inputs finite
    return (short)u;
}

// ---- prep 1: fragment-ordered B blocks (bf16) into ws ----------------------
// F1[kb=sp*2+half][n][lane][j] : half0 = Wk = W1b - W1c, half1 = Wqk = W1d
//   value = B[k = 32*sp + 8*(lane>>4) + j][col = n*16 + (lane&15)]
// F2[s2][n][lane][j]           : W2, k = 32*s2 + 8*(lane>>4) + j
__global__ void prep_frag(const float* __restrict__ W1, const float* __restrict__ W2,
                          short* __restrict__ F1, short* __restrict__ F2) {
    int idx = blockIdx.x * 256 + threadIdx.x;   // 6144 threads
    if (idx < 4096) {
        int lane = idx & 63, n = (idx >> 6) & 7, kb = idx >> 9;
        int q = lane >> 4, l15 = lane & 15;
        int sp = kb >> 1, half = kb & 1;
        int col = n * 16 + l15;
        short8 v;
        #pragma unroll
        for (int j = 0; j < 8; ++j) {
            int k = 32 * sp + 8 * q + j;
            float x = half ? W1[(384 + k) * 128 + col]
                           : W1[(128 + k) * 128 + col] - W1[(256 + k) * 128 + col];
            v[j] = f2bf(x);
        }
        *(short8*)(F1 + idx * 8) = v;
    } else if (idx < 6144) {
        int i2 = idx - 4096;
        int lane = i2 & 63, n = (i2 >> 6) & 7, s2 = i2 >> 9;
        int q = lane >> 4, l15 = lane & 15;
        int col = n * 16 + l15;
        short8 v;
        #pragma unroll
        for (int j = 0; j < 8; ++j)
            v[j] = f2bf(W2[(32 * s2 + 8 * q + j) * 128 + col]);
        *(short8*)(F2 + i2 * 8) = v;
    }
}

// ---- prep 2: qW[b][n] = b1[n] + sum_k q[b][k]*(W1a+W1c)[k][n]  (fp32) ------
__global__ void prep_qw(const float* __restrict__ query, const float* __restrict__ W1,
                        const float* __restrict__ b1, float* __restrict__ qw) {
    __shared__ float qsh[128];
    const int b = blockIdx.x, t = threadIdx.x;   // 128 threads
    qsh[t] = query[b * 128 + t];
    __syncthreads();
    float acc = b1[t];
    #pragma unroll 4
    for (int k = 0; k < 128; ++k)
        acc += qsh[k] * (W1[k * 128 + t] + W1[(256 + k) * 128 + t]);
    qw[b * 128 + t] = acc;
}

// ---- main: one workgroup per batch row -------------------------------------
#define HSTR 136  // h1buf row stride in shorts

__launch_bounds__(256, 2)
__global__ void din_main(const float* __restrict__ query, const float* __restrict__ keys,
                         const int* __restrict__ klen, const float* __restrict__ pos,
                         const float* __restrict__ b2g, const float* __restrict__ w3g,
                         const float* __restrict__ qw, const short* __restrict__ F1,
                         const short* __restrict__ F2, float* __restrict__ out) {
    __shared__ alignas(16) short h1buf[16 * 16 * HSTR];  // 69632 B
    __shared__ float qv[128];
    __shared__ float s_lds[208];
    __shared__ float w_lds[208];
    __shared__ float part[512];
    __shared__ float red[8];

    const int t = threadIdx.x;
    const int b = blockIdx.x;
    const int w = t >> 6;
    const int lane = t & 63;
    const int quad = lane >> 4;
    const int l15 = lane & 15;

    const int len = klen[b];
    const int T = (len + 15) >> 4;                       // tiles actually needed
    const int cnt = (T > w) ? ((T - w + 3) >> 2) : 0;    // this wave's tiles (<=4)

    if (t < 128) qv[t] = query[b * 128 + t];
    __syncthreads();

    f32x4 acc[4][8];
    #pragma unroll
    for (int i = 0; i < 4; ++i)
        #pragma unroll
        for (int n = 0; n < 8; ++n) acc[i][n] = (f32x4){0.f, 0.f, 0.f, 0.f};

    if (cnt > 0) {
        // ---- GEMM1: K=256, A = [kp | kp*q] built from global keys ----
        for (int sp = 0; sp < 4; ++sp) {
            float4 qa = *(const float4*)(qv + 32 * sp + 8 * quad);
            float4 qb = *(const float4*)(qv + 32 * sp + 8 * quad + 4);
            // half 0: kp
            short8 bf[8];
            #pragma unroll
            for (int n = 0; n < 8; ++n)
                bf[n] = *(const short8*)(F1 + (((2 * sp) * 8 + n) * 64 + lane) * 8);
            short8 af[4];
            #pragma unroll
            for (int i = 0; i < 4; ++i) {
                if (i < cnt) {
                    int row = (w + 4 * i) * 16 + l15;
                    short8 a;
                    if (row < 200) {
                        const float* kr = keys + ((long)b * 200 + row) * 128 + 32 * sp + 8 * quad;
                        const float* pr = pos + (long)row * 128 + 32 * sp + 8 * quad;
                        float4 k0 = *(const float4*)kr, k1 = *(const float4*)(kr + 4);
                        float4 p0 = *(const float4*)pr, p1 = *(const float4*)(pr + 4);
                        a[0] = f2bf(k0.x + p0.x); a[1] = f2bf(k0.y + p0.y);
                        a[2] = f2bf(k0.z + p0.z); a[3] = f2bf(k0.w + p0.w);
                        a[4] = f2bf(k1.x + p1.x); a[5] = f2bf(k1.y + p1.y);
                        a[6] = f2bf(k1.z + p1.z); a[7] = f2bf(k1.w + p1.w);
                    } else {
                        #pragma unroll
                        for (int j = 0; j < 8; ++j) a[j] = 0;
                    }
                    af[i] = a;
                    #pragma unroll
                    for (int n = 0; n < 8; ++n)
                        acc[i][n] = __builtin_amdgcn_mfma_f32_16x16x32_bf16(a, bf[n], acc[i][n], 0, 0, 0);
                }
            }
            // half 1: kp * q  (unpack kept kp-frag, scale by q, repack)
            #pragma unroll
            for (int n = 0; n < 8; ++n)
                bf[n] = *(const short8*)(F1 + (((2 * sp + 1) * 8 + n) * 64 + lane) * 8);
            #pragma unroll
            for (int i = 0; i < 4; ++i) {
                if (i < cnt) {
                    short8 a;
                    a[0] = f2bf(bf2f(af[i][0]) * qa.x); a[1] = f2bf(bf2f(af[i][1]) * qa.y);
                    a[2] = f2bf(bf2f(af[i][2]) * qa.z); a[3] = f2bf(bf2f(af[i][3]) * qa.w);
                    a[4] = f2bf(bf2f(af[i][4]) * qb.x); a[5] = f2bf(bf2f(af[i][5]) * qb.y);
                    a[6] = f2bf(bf2f(af[i][6]) * qb.z); a[7] = f2bf(bf2f(af[i][7]) * qb.w);
                    #pragma unroll
                    for (int n = 0; n < 8; ++n)
                        acc[i][n] = __builtin_amdgcn_mfma_f32_16x16x32_bf16(a, bf[n], acc[i][n], 0, 0, 0);
                }
            }
        }

        // ---- h1 = relu(acc + qW) -> LDS (C-layout -> A-layout), same wave ----
        {
            float qwn[8];
            #pragma unroll
            for (int n = 0; n < 8; ++n) qwn[n] = qw[b * 128 + n * 16 + l15];
            #pragma unroll
            for (int i = 0; i < 4; ++i) {
                if (i < cnt) {
                    #pragma unroll
                    for (int n = 0; n < 8; ++n)
                        #pragma unroll
                        for (int r = 0; r < 4; ++r) {
                            float v = acc[i][n][r] + qwn[n];
                            h1buf[((w * 4 + i) * 16 + quad * 4 + r) * HSTR + n * 16 + l15] =
                                f2bf(v > 0.f ? v : 0.f);
                        }
                }
            }
        }

        // ---- GEMM2: h1 @ W2 (K=128), B-frags from global F2 ----
        #pragma unroll
        for (int i = 0; i < 4; ++i)
            #pragma unroll
            for (int n = 0; n < 8; ++n) acc[i][n] = (f32x4){0.f, 0.f, 0.f, 0.f};
        for (int s2 = 0; s2 < 4; ++s2) {
            short8 bf[8];
            #pragma unroll
            for (int n = 0; n < 8; ++n)
                bf[n] = *(const short8*)(F2 + ((s2 * 8 + n) * 64 + lane) * 8);
            #pragma unroll
            for (int i = 0; i < 4; ++i) {
                if (i < cnt) {
                    short8 a = *(const short8*)(h1buf + ((w * 4 + i) * 16 + l15) * HSTR + 32 * s2 + 8 * quad);
                    #pragma unroll
                    for (int n = 0; n < 8; ++n)
                        acc[i][n] = __builtin_amdgcn_mfma_f32_16x16x32_bf16(a, bf[n], acc[i][n], 0, 0, 0);
                }
            }
        }

        // ---- scores: s = sum_n relu(h2 + b2) * W3[n] ----
        {
            float b2n[8], w3n[8];
            #pragma unroll
            for (int n = 0; n < 8; ++n) {
                b2n[n] = b2g[n * 16 + l15];
                w3n[n] = w3g[n * 16 + l15];
            }
            #pragma unroll
            for (int i = 0; i < 4; ++i) {
                if (i < cnt) {
                    float p[4] = {0.f, 0.f, 0.f, 0.f};
                    #pragma unroll
                    for (int n = 0; n < 8; ++n)
                        #pragma unroll
                        for (int r = 0; r < 4; ++r) {
                            float v = acc[i][n][r] + b2n[n];
                            p[r] += (v > 0.f ? v : 0.f) * w3n[n];
                        }
                    #pragma unroll
                    for (int off = 8; off >= 1; off >>= 1)
                        #pragma unroll
                        for (int r = 0; r < 4; ++r) p[r] += __shfl_xor(p[r], off, 64);
                    if (l15 == 0) {
                        #pragma unroll
                        for (int r = 0; r < 4; ++r)
                            s_lds[(w + 4 * i) * 16 + quad * 4 + r] = p[r];
                    }
                }
            }
        }
    }
    __syncthreads();

    // ---- masked softmax over L (b3 dropped: shift-invariant) ----
    float sv = (t < 208 && t < len) ? s_lds[t] : -1e9f;
    float m = sv;
    #pragma unroll
    for (int off = 32; off >= 1; off >>= 1) m = fmaxf(m, __shfl_xor(m, off, 64));
    if (lane == 0) red[w] = m;
    __syncthreads();
    m = fmaxf(fmaxf(red[0], red[1]), fmaxf(red[2], red[3]));
    float e = (t < 208 && t < len) ? expf(sv - m) : 0.f;
    float ssum = e;
    #pragma unroll
    for (int off = 32; off >= 1; off >>= 1) ssum += __shfl_xor(ssum, off, 64);
    if (lane == 0) red[4 + w] = ssum;
    __syncthreads();
    float S = red[4] + red[5] + red[6] + red[7];
    if (t < 208) w_lds[t] = e / S;
    __syncthreads();

    // ---- out[b][e] = sum_{l<len} w[l]*(keys+pos)[l][e]  (keys L2/L3-hot) ----
    const int qt = t >> 6;
    const int e2h = t & 63;          // float2 column pair index
    float ax = 0.f, ay = 0.f;
    const float2* kr = (const float2*)(keys + (long)b * 200 * 128);
    const float2* pr = (const float2*)pos;
    for (int l = qt; l < len; l += 4) {
        float wgt = w_lds[l];
        float2 kv = kr[l * 64 + e2h];
        float2 pv = pr[l * 64 + e2h];
        ax += wgt * (kv.x + pv.x);
        ay += wgt * (kv.y + pv.y);
    }
    part[qt * 128 + 2 * e2h]     = ax;
    part[qt * 128 + 2 * e2h + 1] = ay;
    __syncthreads();
    if (t < 128) {
        float o = part[t] + part[128 + t] + part[256 + t] + part[384 + t];
        out[b * 128 + t] = o;
    }
}

extern "C" void kernel_launch(void* const* d_in, const int* in_sizes, int n_in,
                              void* d_out, int out_size, void* d_ws, size_t ws_size,
                              hipStream_t stream) {
    const float* query = (const float*)d_in[0];
    const float* keys  = (const float*)d_in[1];
    const int*   klen  = (const int*)  d_in[2];
    const float* pos   = (const float*)d_in[3];
    const float* W1    = (const float*)d_in[4];
    const float* b1    = (const float*)d_in[5];
    const float* W2    = (const float*)d_in[6];
    const float* b2    = (const float*)d_in[7];
    const float* W3    = (const float*)d_in[8];
    // d_in[9] = b3: shift-invariant under softmax, unused.
    float* out = (float*)d_out;

    char* ws = (char*)d_ws;
    float* qw = (float*)ws;                    // 4096*128 fp32 = 2 MiB
    short* F1 = (short*)(ws + 2097152);        // 32768 bf16 = 64 KiB
    short* F2 = (short*)(ws + 2097152 + 65536);// 16384 bf16 = 32 KiB

    prep_frag<<<24,   256, 0, stream>>>(W1, W2, F1, F2);
    prep_qw  <<<4096, 128, 0, stream>>>(query, W1, b1, qw);
    din_main <<<4096, 256, 0, stream>>>(query, keys, klen, pos, b2, W3, qw,
                                        F1, F2, out);
}